// Round 5
// baseline (380.567 us; speedup 1.0000x reference)
//
#include <hip/hip_runtime.h>

typedef __bf16 bf16;
typedef __attribute__((ext_vector_type(8))) __bf16 bf16x8;
typedef __attribute__((ext_vector_type(4))) float f32x4;

static __device__ __forceinline__ f32x4 mfma16(bf16x8 a, bf16x8 b, f32x4 c) {
    return __builtin_amdgcn_mfma_f32_16x16x32_bf16(a, b, c, 0, 0, 0);
}

// async global->LDS, 16B per lane; lds base must be wave-uniform
static __device__ __forceinline__ void gll16(const bf16* g, bf16* l) {
    __builtin_amdgcn_global_load_lds(
        (const __attribute__((address_space(1))) unsigned int*)g,
        (__attribute__((address_space(3))) unsigned int*)l, 16, 0, 0);
}

// =====================================================================
// x fp32 -> bf16 (once; result aliased into the Apre workspace slot)
// =====================================================================
__global__ __launch_bounds__(256) void xcvt_kernel(
    const float* __restrict__ x, bf16* __restrict__ xb)
{
    size_t i = ((size_t)blockIdx.x * 256 + threadIdx.x) * 8;
    float4 a0 = *(const float4*)&x[i];
    float4 a1 = *(const float4*)&x[i + 4];
    bf16x8 v = {(bf16)a0.x, (bf16)a0.y, (bf16)a0.z, (bf16)a0.w,
                (bf16)a1.x, (bf16)a1.y, (bf16)a1.z, (bf16)a1.w};
    *(bf16x8*)&xb[i] = v;
}

// =====================================================================
// Weight transpose + convert: W[k][n] (1024x1024 fp32) -> WT[n][k] (bf16)
// =====================================================================
__global__ __launch_bounds__(256) void wtrans_kernel(
    const float* __restrict__ Wq, const float* __restrict__ Wk,
    const float* __restrict__ Wv, const float* __restrict__ Wo,
    bf16* __restrict__ WTqkv, bf16* __restrict__ WTo)
{
    __shared__ bf16 tile[64][65];
    const int bid = blockIdx.x;
    const int mi = bid >> 8;
    const int t  = bid & 255;
    const int tr = t >> 4;
    const int tc = t & 15;
    const int tid = threadIdx.x;

    const float* src = (mi == 0) ? Wq : (mi == 1) ? Wk : (mi == 2) ? Wv : Wo;
    bf16* dst = (mi < 3) ? (WTqkv + (size_t)mi * 1024 * 1024) : WTo;

    #pragma unroll
    for (int i = 0; i < 16; i++) {
        int idx = i * 256 + tid;
        int rl = idx >> 6, cl = idx & 63;
        tile[rl][cl] = (bf16)src[(size_t)(tr * 64 + rl) * 1024 + tc * 64 + cl];
    }
    __syncthreads();
    #pragma unroll
    for (int i = 0; i < 16; i++) {
        int idx = i * 256 + tid;
        int rl = idx >> 6, cl = idx & 63;
        dst[(size_t)(tc * 64 + rl) * 1024 + tr * 64 + cl] = tile[cl][rl];
    }
}

// bias concat (fp32): [b_q | b_k | b_v] -> 3072 floats
__global__ void biascat_kernel(const float* __restrict__ bq, const float* __restrict__ bk,
                               const float* __restrict__ bv, float* __restrict__ dst)
{
    int i = blockIdx.x * 256 + threadIdx.x;
    if (i < 1024) dst[i] = bq[i];
    else if (i < 2048) dst[i] = bk[i - 1024];
    else dst[i] = bv[i - 2048];
}

// =====================================================================
// m97-style GEMM: A bf16, BT bf16, global_load_lds(16B) staging.
// C = A @ BT^T + bias, bf16 out; cols<1024 scaled by 0.125 if scaleQ.
// Tile 128x128x32, 4 waves, 64x64 per wave (4x4 16x16x32 frags).
// =====================================================================
__global__ __launch_bounds__(256) void gemm_bf16_kernel(
    const bf16* __restrict__ A, const bf16* __restrict__ BT,
    const float* __restrict__ bias, bf16* __restrict__ C,
    int M, int N, int K, int scaleQ)
{
    __shared__ bf16 sA[128 * 32];
    __shared__ bf16 sB[128 * 32];
    const int tid  = threadIdx.x;
    const int lane = tid & 63;
    const int wave = tid >> 6;
    const int quad = lane >> 4;
    const int l15  = lane & 15;
    const int wm = (wave >> 1) * 64;
    const int wn = (wave & 1) * 64;
    const int m0 = blockIdx.y * 128;
    const int n0 = blockIdx.x * 128;

    const f32x4 fzero = {0.f, 0.f, 0.f, 0.f};
    f32x4 acc[4][4];
    #pragma unroll
    for (int i = 0; i < 4; i++)
        #pragma unroll
        for (int j = 0; j < 4; j++) acc[i][j] = fzero;

    float bv[4];
    #pragma unroll
    for (int nc = 0; nc < 4; nc++) bv[nc] = bias[n0 + wn + nc * 16 + l15];

    const int rA = lane >> 2;          // row within 16-row group
    const int cA = (lane & 3) * 8;     // k-offset (8 bf16 = 16B)

    for (int k0 = 0; k0 < K; k0 += 32) {
        #pragma unroll
        for (int p = 0; p < 2; p++) {
            int r16 = (wave * 2 + p) * 16;
            gll16(&A[(size_t)(m0 + r16 + rA) * K + k0 + cA], &sA[r16 * 32]);
            gll16(&BT[(size_t)(n0 + r16 + rA) * K + k0 + cA], &sB[r16 * 32]);
        }
        __syncthreads();

        bf16x8 aF[4], bF[4];
        #pragma unroll
        for (int mc = 0; mc < 4; mc++)
            aF[mc] = *(const bf16x8*)&sA[(wm + mc * 16 + l15) * 32 + quad * 8];
        #pragma unroll
        for (int nc = 0; nc < 4; nc++)
            bF[nc] = *(const bf16x8*)&sB[(wn + nc * 16 + l15) * 32 + quad * 8];

        #pragma unroll
        for (int mc = 0; mc < 4; mc++)
            #pragma unroll
            for (int nc = 0; nc < 4; nc++)
                acc[mc][nc] = mfma16(aF[mc], bF[nc], acc[mc][nc]);
        __syncthreads();
    }

    const float sc = (scaleQ && n0 < 1024) ? 0.125f : 1.0f;
    #pragma unroll
    for (int mc = 0; mc < 4; mc++) {
        #pragma unroll
        for (int reg = 0; reg < 4; reg++) {
            int row = m0 + wm + mc * 16 + quad * 4 + reg;
            size_t base = (size_t)row * N + n0 + wn;
            #pragma unroll
            for (int nc = 0; nc < 4; nc++)
                C[base + nc * 16 + l15] = (bf16)((acc[mc][nc][reg] + bv[nc]) * sc);
        }
    }
}

// Same structure, fp32 output (final projection -> d_out)
__global__ __launch_bounds__(256) void gemm_bf16_f32out_kernel(
    const bf16* __restrict__ A, const bf16* __restrict__ BT,
    const float* __restrict__ bias, float* __restrict__ C,
    int M, int N, int K)
{
    __shared__ bf16 sA[128 * 32];
    __shared__ bf16 sB[128 * 32];
    const int tid  = threadIdx.x;
    const int lane = tid & 63;
    const int wave = tid >> 6;
    const int quad = lane >> 4;
    const int l15  = lane & 15;
    const int wm = (wave >> 1) * 64;
    const int wn = (wave & 1) * 64;
    const int m0 = blockIdx.y * 128;
    const int n0 = blockIdx.x * 128;

    const f32x4 fzero = {0.f, 0.f, 0.f, 0.f};
    f32x4 acc[4][4];
    #pragma unroll
    for (int i = 0; i < 4; i++)
        #pragma unroll
        for (int j = 0; j < 4; j++) acc[i][j] = fzero;

    float bv[4];
    #pragma unroll
    for (int nc = 0; nc < 4; nc++) bv[nc] = bias[n0 + wn + nc * 16 + l15];

    const int rA = lane >> 2;
    const int cA = (lane & 3) * 8;

    for (int k0 = 0; k0 < K; k0 += 32) {
        #pragma unroll
        for (int p = 0; p < 2; p++) {
            int r16 = (wave * 2 + p) * 16;
            gll16(&A[(size_t)(m0 + r16 + rA) * K + k0 + cA], &sA[r16 * 32]);
            gll16(&BT[(size_t)(n0 + r16 + rA) * K + k0 + cA], &sB[r16 * 32]);
        }
        __syncthreads();

        bf16x8 aF[4], bF[4];
        #pragma unroll
        for (int mc = 0; mc < 4; mc++)
            aF[mc] = *(const bf16x8*)&sA[(wm + mc * 16 + l15) * 32 + quad * 8];
        #pragma unroll
        for (int nc = 0; nc < 4; nc++)
            bF[nc] = *(const bf16x8*)&sB[(wn + nc * 16 + l15) * 32 + quad * 8];

        #pragma unroll
        for (int mc = 0; mc < 4; mc++)
            #pragma unroll
            for (int nc = 0; nc < 4; nc++)
                acc[mc][nc] = mfma16(aF[mc], bF[nc], acc[mc][nc]);
        __syncthreads();
    }

    #pragma unroll
    for (int mc = 0; mc < 4; mc++) {
        #pragma unroll
        for (int reg = 0; reg < 4; reg++) {
            int row = m0 + wm + mc * 16 + quad * 4 + reg;
            size_t base = (size_t)row * N + n0 + wn;
            #pragma unroll
            for (int nc = 0; nc < 4; nc++)
                C[base + nc * 16 + l15] = acc[mc][nc][reg] + bv[nc];
        }
    }
}

// =====================================================================
// V transpose: QKVp[b][n][2048 + h*64 + d] -> Vt[b*16+h][d][n]
// =====================================================================
__global__ __launch_bounds__(256) void vtrans_kernel(
    const bf16* __restrict__ QKVp, bf16* __restrict__ Vt)
{
    __shared__ bf16 tile[64][65];
    const int bid = blockIdx.x;
    const int bh = bid >> 5;
    const int nt = bid & 31;
    const int b = bh >> 4, h = bh & 15;
    const int tid = threadIdx.x;

    #pragma unroll
    for (int i = 0; i < 16; i++) {
        int idx = i * 256 + tid;
        int rl = idx >> 6, cl = idx & 63;
        tile[rl][cl] = QKVp[(size_t)(b * 2048 + nt * 64 + rl) * 3072 + 2048 + h * 64 + cl];
    }
    __syncthreads();
    #pragma unroll
    for (int i = 0; i < 16; i++) {
        int idx = i * 256 + tid;
        int rl = idx >> 6, cl = idx & 63;
        Vt[((size_t)bh * 64 + rl) * 2048 + nt * 64 + cl] = tile[cl][rl];
    }
}

// =====================================================================
// Flash attention, fixed-max softmax, 32 q-rows per wave:
// block = (b,h, 128 q-rows), 4 waves; 64-key tiles; K/V frags shared
// across the wave's two q-groups (halves LDS reads per MFMA).
// =====================================================================
#define LSTR 72
__global__ __launch_bounds__(256) void attn_kernel(
    const bf16* __restrict__ QKV, const bf16* __restrict__ Vt,
    bf16* __restrict__ Opre)
{
    __shared__ bf16 sK[64 * LSTR];      // [key][d]
    __shared__ bf16 sV[64 * LSTR];      // [d][key]
    __shared__ bf16 sP[4][32 * LSTR];   // per-wave [q][key]

    const int tid  = threadIdx.x;
    const int lane = tid & 63;
    const int w    = tid >> 6;
    const int quad = lane >> 4;
    const int l15  = lane & 15;
    const int bid = blockIdx.x;
    const int bh = bid >> 4;        // 0..63
    const int qt = bid & 15;
    const int b = bh >> 4, h = bh & 15;
    const int q0 = qt * 128;

    // Q fragments, two 16-row groups per wave (Q pre-scaled by 0.125)
    bf16x8 qF[2][2];
    #pragma unroll
    for (int g = 0; g < 2; g++) {
        size_t qrow = (size_t)(b * 2048 + q0 + w * 32 + g * 16 + l15) * 3072 + h * 64;
        qF[g][0] = *(const bf16x8*)&QKV[qrow + quad * 8];
        qF[g][1] = *(const bf16x8*)&QKV[qrow + 32 + quad * 8];
    }

    const f32x4 fzero = {0.f, 0.f, 0.f, 0.f};
    float psum[2][4] = {{0.f,0.f,0.f,0.f},{0.f,0.f,0.f,0.f}};
    f32x4 o[2][4];
    #pragma unroll
    for (int g = 0; g < 2; g++)
        #pragma unroll
        for (int d = 0; d < 4; d++) o[g][d] = fzero;

    const int srow = tid >> 3, sseg = tid & 7;    // staging: 64 rows x 8 segs
    const size_t kbase = (size_t)(b * 2048) * 3072 + 1024 + h * 64;
    const size_t vbase = (size_t)bh * 64 * 2048;

    for (int key0 = 0; key0 < 2048; key0 += 64) {
        #pragma unroll
        for (int p = 0; p < 2; p++) {
            int row = srow + p * 32;
            *(bf16x8*)&sK[row * LSTR + sseg * 8] =
                *(const bf16x8*)&QKV[kbase + (size_t)(key0 + row) * 3072 + sseg * 8];
            *(bf16x8*)&sV[row * LSTR + sseg * 8] =
                *(const bf16x8*)&Vt[vbase + (size_t)row * 2048 + key0 + sseg * 8];
        }
        __syncthreads();

        // S = Q K^T : 32 q-rows x 64 keys; K frags shared across q-groups
        f32x4 s[2][4];
        #pragma unroll
        for (int c = 0; c < 4; c++) {
            bf16x8 k0 = *(const bf16x8*)&sK[(c * 16 + l15) * LSTR + quad * 8];
            bf16x8 k1 = *(const bf16x8*)&sK[(c * 16 + l15) * LSTR + 32 + quad * 8];
            #pragma unroll
            for (int g = 0; g < 2; g++) {
                s[g][c] = mfma16(qF[g][0], k0, fzero);
                s[g][c] = mfma16(qF[g][1], k1, s[g][c]);
            }
        }

        // p = exp(s); C->A layout via per-wave sP; accumulate row-sums
        #pragma unroll
        for (int g = 0; g < 2; g++)
            #pragma unroll
            for (int c = 0; c < 4; c++)
                #pragma unroll
                for (int r = 0; r < 4; r++) {
                    float p = __expf(s[g][c][r]);
                    sP[w][(g * 16 + quad * 4 + r) * LSTR + c * 16 + l15] = (bf16)p;
                    psum[g][r] += p;
                }

        // O += P V : V frags shared across q-groups
        #pragma unroll
        for (int c2 = 0; c2 < 2; c2++) {
            bf16x8 vB[4];
            #pragma unroll
            for (int d = 0; d < 4; d++)
                vB[d] = *(const bf16x8*)&sV[(d * 16 + l15) * LSTR + c2 * 32 + quad * 8];
            #pragma unroll
            for (int g = 0; g < 2; g++) {
                bf16x8 pA = *(const bf16x8*)&sP[w][(g * 16 + l15) * LSTR + c2 * 32 + quad * 8];
                #pragma unroll
                for (int d = 0; d < 4; d++)
                    o[g][d] = mfma16(pA, vB[d], o[g][d]);
            }
        }
        __syncthreads();   // before next tile overwrites sK/sV
    }

    #pragma unroll
    for (int g = 0; g < 2; g++)
        #pragma unroll
        for (int r = 0; r < 4; r++) {
            float t = psum[g][r];
            t += __shfl_xor(t, 1);
            t += __shfl_xor(t, 2);
            t += __shfl_xor(t, 4);
            t += __shfl_xor(t, 8);
            float inv = 1.0f / t;
            int row = q0 + w * 32 + g * 16 + quad * 4 + r;
            size_t base = (size_t)(b * 2048 + row) * 1024 + h * 64;
            #pragma unroll
            for (int d = 0; d < 4; d++)
                Opre[base + d * 16 + l15] = (bf16)(o[g][d][r] * inv);
        }
}

// =====================================================================
extern "C" void kernel_launch(void* const* d_in, const int* in_sizes, int n_in,
                              void* d_out, int out_size, void* d_ws, size_t ws_size,
                              hipStream_t stream)
{
    const float* x  = (const float*)d_in[0];
    const float* Wq = (const float*)d_in[1];
    const float* bq = (const float*)d_in[2];
    const float* Wk = (const float*)d_in[3];
    const float* bk = (const float*)d_in[4];
    const float* Wv = (const float*)d_in[5];
    const float* bv = (const float*)d_in[6];
    const float* Wo = (const float*)d_in[7];
    const float* bo = (const float*)d_in[8];
    float* out = (float*)d_out;

    bf16* WTqkv = (bf16*)d_ws;                         // 3072*1024 bf16
    bf16* WTo   = WTqkv + (size_t)3072 * 1024;         // 1024*1024 bf16
    float* bcat = (float*)(WTo + (size_t)1024 * 1024); // 3072 f32 (pad 4096)
    bf16* QKVp  = (bf16*)(bcat + 4096);                // 8192*3072 bf16
    bf16* Vt    = QKVp + (size_t)8192 * 3072;          // 64*64*2048 bf16
    bf16* Apre  = Vt + (size_t)64 * 64 * 2048;         // 8192*1024 bf16
    bf16* xb    = Apre;   // alias: x-as-bf16 lives here until attn overwrites
    (void)ws_size; (void)n_in; (void)in_sizes; (void)out_size;

    xcvt_kernel<<<4096, 256, 0, stream>>>(x, xb);
    wtrans_kernel<<<1024, 256, 0, stream>>>(Wq, Wk, Wv, Wo, WTqkv, WTo);
    biascat_kernel<<<12, 256, 0, stream>>>(bq, bk, bv, bcat);
    gemm_bf16_kernel<<<dim3(24, 64), 256, 0, stream>>>(xb, WTqkv, bcat, QKVp, 8192, 3072, 1024, 1);
    vtrans_kernel<<<2048, 256, 0, stream>>>(QKVp, Vt);
    attn_kernel<<<1024, 256, 0, stream>>>(QKVp, Vt, Apre);
    gemm_bf16_f32out_kernel<<<dim3(8, 64), 256, 0, stream>>>(Apre, WTo, bo, out, 8192, 1024, 1024);
}

// Round 6
// 350.908 us; speedup vs baseline: 1.0845x; 1.0845x over previous
//
#include <hip/hip_runtime.h>

typedef __bf16 bf16;
typedef __attribute__((ext_vector_type(8))) __bf16 bf16x8;
typedef __attribute__((ext_vector_type(4))) float f32x4;

static __device__ __forceinline__ f32x4 mfma16(bf16x8 a, bf16x8 b, f32x4 c) {
    return __builtin_amdgcn_mfma_f32_16x16x32_bf16(a, b, c, 0, 0, 0);
}

// async global->LDS, 16B per lane; lds base must be wave-uniform
static __device__ __forceinline__ void gll16(const bf16* g, bf16* l) {
    __builtin_amdgcn_global_load_lds(
        (const __attribute__((address_space(1))) unsigned int*)g,
        (__attribute__((address_space(3))) unsigned int*)l, 16, 0, 0);
}

// =====================================================================
// x fp32 -> bf16 (once; result aliased into the Apre workspace slot)
// =====================================================================
__global__ __launch_bounds__(256) void xcvt_kernel(
    const float* __restrict__ x, bf16* __restrict__ xb)
{
    size_t i = ((size_t)blockIdx.x * 256 + threadIdx.x) * 8;
    float4 a0 = *(const float4*)&x[i];
    float4 a1 = *(const float4*)&x[i + 4];
    bf16x8 v = {(bf16)a0.x, (bf16)a0.y, (bf16)a0.z, (bf16)a0.w,
                (bf16)a1.x, (bf16)a1.y, (bf16)a1.z, (bf16)a1.w};
    *(bf16x8*)&xb[i] = v;
}

// =====================================================================
// Weight transpose + convert: W[k][n] (1024x1024 fp32) -> WT[n][k] (bf16)
// =====================================================================
__global__ __launch_bounds__(256) void wtrans_kernel(
    const float* __restrict__ Wq, const float* __restrict__ Wk,
    const float* __restrict__ Wv, const float* __restrict__ Wo,
    bf16* __restrict__ WTqkv, bf16* __restrict__ WTo)
{
    __shared__ bf16 tile[64][65];
    const int bid = blockIdx.x;
    const int mi = bid >> 8;
    const int t  = bid & 255;
    const int tr = t >> 4;
    const int tc = t & 15;
    const int tid = threadIdx.x;

    const float* src = (mi == 0) ? Wq : (mi == 1) ? Wk : (mi == 2) ? Wv : Wo;
    bf16* dst = (mi < 3) ? (WTqkv + (size_t)mi * 1024 * 1024) : WTo;

    #pragma unroll
    for (int i = 0; i < 16; i++) {
        int idx = i * 256 + tid;
        int rl = idx >> 6, cl = idx & 63;
        tile[rl][cl] = (bf16)src[(size_t)(tr * 64 + rl) * 1024 + tc * 64 + cl];
    }
    __syncthreads();
    #pragma unroll
    for (int i = 0; i < 16; i++) {
        int idx = i * 256 + tid;
        int rl = idx >> 6, cl = idx & 63;
        dst[(size_t)(tc * 64 + rl) * 1024 + tr * 64 + cl] = tile[cl][rl];
    }
}

// bias concat (fp32): [b_q | b_k | b_v] -> 3072 floats
__global__ void biascat_kernel(const float* __restrict__ bq, const float* __restrict__ bk,
                               const float* __restrict__ bv, float* __restrict__ dst)
{
    int i = blockIdx.x * 256 + threadIdx.x;
    if (i < 1024) dst[i] = bq[i];
    else if (i < 2048) dst[i] = bk[i - 1024];
    else dst[i] = bv[i - 2048];
}

// =====================================================================
// m97-style GEMM: A bf16, BT bf16, global_load_lds(16B) staging.
// C = A @ BT^T + bias, bf16 out; cols<1024 scaled by QSCALE if scaleQ
// (folds 1/sqrt(d_k) * log2(e) into Q so softmax is a bare exp2).
// =====================================================================
#define QSCALE 0.18033688011112043f   // 0.125 * log2(e)
__global__ __launch_bounds__(256) void gemm_bf16_kernel(
    const bf16* __restrict__ A, const bf16* __restrict__ BT,
    const float* __restrict__ bias, bf16* __restrict__ C,
    int M, int N, int K, int scaleQ)
{
    __shared__ bf16 sA[128 * 32];
    __shared__ bf16 sB[128 * 32];
    const int tid  = threadIdx.x;
    const int lane = tid & 63;
    const int wave = tid >> 6;
    const int quad = lane >> 4;
    const int l15  = lane & 15;
    const int wm = (wave >> 1) * 64;
    const int wn = (wave & 1) * 64;
    const int m0 = blockIdx.y * 128;
    const int n0 = blockIdx.x * 128;

    const f32x4 fzero = {0.f, 0.f, 0.f, 0.f};
    f32x4 acc[4][4];
    #pragma unroll
    for (int i = 0; i < 4; i++)
        #pragma unroll
        for (int j = 0; j < 4; j++) acc[i][j] = fzero;

    float bv[4];
    #pragma unroll
    for (int nc = 0; nc < 4; nc++) bv[nc] = bias[n0 + wn + nc * 16 + l15];

    const int rA = lane >> 2;
    const int cA = (lane & 3) * 8;

    for (int k0 = 0; k0 < K; k0 += 32) {
        #pragma unroll
        for (int p = 0; p < 2; p++) {
            int r16 = (wave * 2 + p) * 16;
            gll16(&A[(size_t)(m0 + r16 + rA) * K + k0 + cA], &sA[r16 * 32]);
            gll16(&BT[(size_t)(n0 + r16 + rA) * K + k0 + cA], &sB[r16 * 32]);
        }
        __syncthreads();

        bf16x8 aF[4], bF[4];
        #pragma unroll
        for (int mc = 0; mc < 4; mc++)
            aF[mc] = *(const bf16x8*)&sA[(wm + mc * 16 + l15) * 32 + quad * 8];
        #pragma unroll
        for (int nc = 0; nc < 4; nc++)
            bF[nc] = *(const bf16x8*)&sB[(wn + nc * 16 + l15) * 32 + quad * 8];

        #pragma unroll
        for (int mc = 0; mc < 4; mc++)
            #pragma unroll
            for (int nc = 0; nc < 4; nc++)
                acc[mc][nc] = mfma16(aF[mc], bF[nc], acc[mc][nc]);
        __syncthreads();
    }

    const float sc = (scaleQ && n0 < 1024) ? QSCALE : 1.0f;
    #pragma unroll
    for (int mc = 0; mc < 4; mc++) {
        #pragma unroll
        for (int reg = 0; reg < 4; reg++) {
            int row = m0 + wm + mc * 16 + quad * 4 + reg;
            size_t base = (size_t)row * N + n0 + wn;
            #pragma unroll
            for (int nc = 0; nc < 4; nc++)
                C[base + nc * 16 + l15] = (bf16)((acc[mc][nc][reg] + bv[nc]) * sc);
        }
    }
}

// Same structure, fp32 output (final projection -> d_out)
__global__ __launch_bounds__(256) void gemm_bf16_f32out_kernel(
    const bf16* __restrict__ A, const bf16* __restrict__ BT,
    const float* __restrict__ bias, float* __restrict__ C,
    int M, int N, int K)
{
    __shared__ bf16 sA[128 * 32];
    __shared__ bf16 sB[128 * 32];
    const int tid  = threadIdx.x;
    const int lane = tid & 63;
    const int wave = tid >> 6;
    const int quad = lane >> 4;
    const int l15  = lane & 15;
    const int wm = (wave >> 1) * 64;
    const int wn = (wave & 1) * 64;
    const int m0 = blockIdx.y * 128;
    const int n0 = blockIdx.x * 128;

    const f32x4 fzero = {0.f, 0.f, 0.f, 0.f};
    f32x4 acc[4][4];
    #pragma unroll
    for (int i = 0; i < 4; i++)
        #pragma unroll
        for (int j = 0; j < 4; j++) acc[i][j] = fzero;

    float bv[4];
    #pragma unroll
    for (int nc = 0; nc < 4; nc++) bv[nc] = bias[n0 + wn + nc * 16 + l15];

    const int rA = lane >> 2;
    const int cA = (lane & 3) * 8;

    for (int k0 = 0; k0 < K; k0 += 32) {
        #pragma unroll
        for (int p = 0; p < 2; p++) {
            int r16 = (wave * 2 + p) * 16;
            gll16(&A[(size_t)(m0 + r16 + rA) * K + k0 + cA], &sA[r16 * 32]);
            gll16(&BT[(size_t)(n0 + r16 + rA) * K + k0 + cA], &sB[r16 * 32]);
        }
        __syncthreads();

        bf16x8 aF[4], bF[4];
        #pragma unroll
        for (int mc = 0; mc < 4; mc++)
            aF[mc] = *(const bf16x8*)&sA[(wm + mc * 16 + l15) * 32 + quad * 8];
        #pragma unroll
        for (int nc = 0; nc < 4; nc++)
            bF[nc] = *(const bf16x8*)&sB[(wn + nc * 16 + l15) * 32 + quad * 8];

        #pragma unroll
        for (int mc = 0; mc < 4; mc++)
            #pragma unroll
            for (int nc = 0; nc < 4; nc++)
                acc[mc][nc] = mfma16(aF[mc], bF[nc], acc[mc][nc]);
        __syncthreads();
    }

    #pragma unroll
    for (int mc = 0; mc < 4; mc++) {
        #pragma unroll
        for (int reg = 0; reg < 4; reg++) {
            int row = m0 + wm + mc * 16 + quad * 4 + reg;
            size_t base = (size_t)row * N + n0 + wn;
            #pragma unroll
            for (int nc = 0; nc < 4; nc++)
                C[base + nc * 16 + l15] = acc[mc][nc][reg] + bv[nc];
        }
    }
}

// =====================================================================
// V transpose: QKVp[b][n][2048 + h*64 + d] -> Vt[b*16+h][d][n]
// =====================================================================
__global__ __launch_bounds__(256) void vtrans_kernel(
    const bf16* __restrict__ QKVp, bf16* __restrict__ Vt)
{
    __shared__ bf16 tile[64][65];
    const int bid = blockIdx.x;
    const int bh = bid >> 5;
    const int nt = bid & 31;
    const int b = bh >> 4, h = bh & 15;
    const int tid = threadIdx.x;

    #pragma unroll
    for (int i = 0; i < 16; i++) {
        int idx = i * 256 + tid;
        int rl = idx >> 6, cl = idx & 63;
        tile[rl][cl] = QKVp[(size_t)(b * 2048 + nt * 64 + rl) * 3072 + 2048 + h * 64 + cl];
    }
    __syncthreads();
    #pragma unroll
    for (int i = 0; i < 16; i++) {
        int idx = i * 256 + tid;
        int rl = idx >> 6, cl = idx & 63;
        Vt[((size_t)bh * 64 + rl) * 2048 + nt * 64 + cl] = tile[cl][rl];
    }
}

// =====================================================================
// Flash attention, fixed-max exp2 softmax (scales pre-folded into Q).
// Block = (b,h, 64 q-rows): 4 waves x 16 q-rows; 64-key tiles.
// XOR-swizzled LDS, stride 64 elems (128B rows), 16B granules:
//   phys_granule = logical_granule ^ (row & 7)
// -> all LDS stores/reads <=2-way (free), zero padding, 24 KB/block.
// =====================================================================
__global__ __launch_bounds__(256) void attn_kernel(
    const bf16* __restrict__ QKV, const bf16* __restrict__ Vt,
    bf16* __restrict__ Opre)
{
    __shared__ bf16 sK[64 * 64];      // [key][d], swizzled
    __shared__ bf16 sV[64 * 64];      // [d][key], swizzled
    __shared__ bf16 sP[4][16 * 64];   // per-wave [q][key], swizzled

    const int tid  = threadIdx.x;
    const int lane = tid & 63;
    const int w    = tid >> 6;
    const int quad = lane >> 4;
    const int l15  = lane & 15;
    const int bid = blockIdx.x;
    const int bh = bid >> 5;        // 0..63
    const int qt = bid & 31;
    const int b = bh >> 4, h = bh & 15;
    const int q0 = qt * 64;

    // Q fragments (A-operand: m=l15, k=quad*8+j); Q pre-scaled by 0.125*log2e
    size_t qrow = (size_t)(b * 2048 + q0 + w * 16 + l15) * 3072 + h * 64;
    bf16x8 qF0 = *(const bf16x8*)&QKV[qrow + quad * 8];
    bf16x8 qF1 = *(const bf16x8*)&QKV[qrow + 32 + quad * 8];

    const f32x4 fzero = {0.f, 0.f, 0.f, 0.f};
    float psum[4] = {0.f, 0.f, 0.f, 0.f};
    f32x4 o[4];
    #pragma unroll
    for (int d = 0; d < 4; d++) o[d] = fzero;

    const int srow = tid >> 3, sseg = tid & 7;    // staging: 64 rows x 8 granules
    const size_t kbase = (size_t)(b * 2048) * 3072 + 1024 + h * 64;
    const size_t vbase = (size_t)bh * 64 * 2048;

    for (int key0 = 0; key0 < 2048; key0 += 64) {
        #pragma unroll
        for (int p = 0; p < 2; p++) {
            int row = srow + p * 32;
            int sg = sseg ^ (row & 7);
            *(bf16x8*)&sK[row * 64 + sg * 8] =
                *(const bf16x8*)&QKV[kbase + (size_t)(key0 + row) * 3072 + sseg * 8];
            *(bf16x8*)&sV[row * 64 + sg * 8] =
                *(const bf16x8*)&Vt[vbase + (size_t)row * 2048 + key0 + sseg * 8];
        }
        __syncthreads();

        // S = Q K^T : 16 q-rows x 64 keys (4 chunks of 16 keys)
        f32x4 s[4];
        #pragma unroll
        for (int c = 0; c < 4; c++) {
            int kr = c * 16 + l15;
            int sw = kr & 7;
            bf16x8 k0 = *(const bf16x8*)&sK[kr * 64 + ((quad ^ sw) * 8)];
            bf16x8 k1 = *(const bf16x8*)&sK[kr * 64 + (((4 + quad) ^ sw) * 8)];
            s[c] = mfma16(qF0, k0, fzero);
            s[c] = mfma16(qF1, k1, s[c]);
        }

        // p = exp2(s) (log2e folded into Q); C->A layout via swizzled sP
        #pragma unroll
        for (int c = 0; c < 4; c++) {
            #pragma unroll
            for (int r = 0; r < 4; r++) {
                float p = __builtin_amdgcn_exp2f(s[c][r]);
                int q = quad * 4 + r;
                int pg = (c * 2 + (l15 >> 3)) ^ (q & 7);
                sP[w][q * 64 + pg * 8 + (l15 & 7)] = (bf16)p;
                psum[r] += p;
            }
        }
        // same-wave sP store->load ordering via lgkmcnt (sP is per-wave)

        // O += P V : two 32-key k-chunks
        #pragma unroll
        for (int c2 = 0; c2 < 2; c2++) {
            int swp = l15 & 7;
            bf16x8 pA = *(const bf16x8*)&sP[w][l15 * 64 + (((c2 * 4 + quad) ^ swp) * 8)];
            #pragma unroll
            for (int d = 0; d < 4; d++) {
                int dr = d * 16 + l15;
                bf16x8 vB = *(const bf16x8*)&sV[dr * 64 + (((c2 * 4 + quad) ^ (dr & 7)) * 8)];
                o[d] = mfma16(pA, vB, o[d]);
            }
        }
        __syncthreads();   // before next tile overwrites sK/sV
    }

    // final row-sum reduce across 16-lane key groups, then normalize
    #pragma unroll
    for (int r = 0; r < 4; r++) {
        float t = psum[r];
        t += __shfl_xor(t, 1);
        t += __shfl_xor(t, 2);
        t += __shfl_xor(t, 4);
        t += __shfl_xor(t, 8);
        float inv = 1.0f / t;
        int row = q0 + w * 16 + quad * 4 + r;
        size_t base = (size_t)(b * 2048 + row) * 1024 + h * 64;
        #pragma unroll
        for (int d = 0; d < 4; d++)
            Opre[base + d * 16 + l15] = (bf16)(o[d][r] * inv);
    }
}

// =====================================================================
extern "C" void kernel_launch(void* const* d_in, const int* in_sizes, int n_in,
                              void* d_out, int out_size, void* d_ws, size_t ws_size,
                              hipStream_t stream)
{
    const float* x  = (const float*)d_in[0];
    const float* Wq = (const float*)d_in[1];
    const float* bq = (const float*)d_in[2];
    const float* Wk = (const float*)d_in[3];
    const float* bk = (const float*)d_in[4];
    const float* Wv = (const float*)d_in[5];
    const float* bv = (const float*)d_in[6];
    const float* Wo = (const float*)d_in[7];
    const float* bo = (const float*)d_in[8];
    float* out = (float*)d_out;

    bf16* WTqkv = (bf16*)d_ws;                         // 3072*1024 bf16
    bf16* WTo   = WTqkv + (size_t)3072 * 1024;         // 1024*1024 bf16
    float* bcat = (float*)(WTo + (size_t)1024 * 1024); // 3072 f32 (pad 4096)
    bf16* QKVp  = (bf16*)(bcat + 4096);                // 8192*3072 bf16
    bf16* Vt    = QKVp + (size_t)8192 * 3072;          // 64*64*2048 bf16
    bf16* Apre  = Vt + (size_t)64 * 64 * 2048;         // 8192*1024 bf16
    bf16* xb    = Apre;   // alias: x-as-bf16 lives here until attn overwrites
    (void)ws_size; (void)n_in; (void)in_sizes; (void)out_size;

    xcvt_kernel<<<4096, 256, 0, stream>>>(x, xb);
    wtrans_kernel<<<1024, 256, 0, stream>>>(Wq, Wk, Wv, Wo, WTqkv, WTo);
    biascat_kernel<<<12, 256, 0, stream>>>(bq, bk, bv, bcat);
    gemm_bf16_kernel<<<dim3(24, 64), 256, 0, stream>>>(xb, WTqkv, bcat, QKVp, 8192, 3072, 1024, 1);
    vtrans_kernel<<<2048, 256, 0, stream>>>(QKVp, Vt);
    attn_kernel<<<2048, 256, 0, stream>>>(QKVp, Vt, Apre);
    gemm_bf16_f32out_kernel<<<dim3(8, 64), 256, 0, stream>>>(Apre, WTo, bo, out, 8192, 1024, 1024);
}

// Round 7
// 337.066 us; speedup vs baseline: 1.1291x; 1.0411x over previous
//
#include <hip/hip_runtime.h>

typedef __bf16 bf16;
typedef __attribute__((ext_vector_type(8))) __bf16 bf16x8;
typedef __attribute__((ext_vector_type(4))) __bf16 bf16x4;
typedef __attribute__((ext_vector_type(4))) float f32x4;

static __device__ __forceinline__ f32x4 mfma16(bf16x8 a, bf16x8 b, f32x4 c) {
    return __builtin_amdgcn_mfma_f32_16x16x32_bf16(a, b, c, 0, 0, 0);
}

// async global->LDS, 16B per lane; lds base must be wave-uniform
static __device__ __forceinline__ void gll16(const bf16* g, bf16* l) {
    __builtin_amdgcn_global_load_lds(
        (const __attribute__((address_space(1))) unsigned int*)g,
        (__attribute__((address_space(3))) unsigned int*)l, 16, 0, 0);
}

// =====================================================================
// x fp32 -> bf16 (once; result aliased into the Apre workspace slot)
// =====================================================================
__global__ __launch_bounds__(256) void xcvt_kernel(
    const float* __restrict__ x, bf16* __restrict__ xb)
{
    size_t i = ((size_t)blockIdx.x * 256 + threadIdx.x) * 8;
    float4 a0 = *(const float4*)&x[i];
    float4 a1 = *(const float4*)&x[i + 4];
    bf16x8 v = {(bf16)a0.x, (bf16)a0.y, (bf16)a0.z, (bf16)a0.w,
                (bf16)a1.x, (bf16)a1.y, (bf16)a1.z, (bf16)a1.w};
    *(bf16x8*)&xb[i] = v;
}

// =====================================================================
// Weight transpose + convert: W[k][n] (1024x1024 fp32) -> WT[n][k] (bf16)
// =====================================================================
__global__ __launch_bounds__(256) void wtrans_kernel(
    const float* __restrict__ Wq, const float* __restrict__ Wk,
    const float* __restrict__ Wv, const float* __restrict__ Wo,
    bf16* __restrict__ WTqkv, bf16* __restrict__ WTo)
{
    __shared__ bf16 tile[64][65];
    const int bid = blockIdx.x;
    const int mi = bid >> 8;
    const int t  = bid & 255;
    const int tr = t >> 4;
    const int tc = t & 15;
    const int tid = threadIdx.x;

    const float* src = (mi == 0) ? Wq : (mi == 1) ? Wk : (mi == 2) ? Wv : Wo;
    bf16* dst = (mi < 3) ? (WTqkv + (size_t)mi * 1024 * 1024) : WTo;

    #pragma unroll
    for (int i = 0; i < 16; i++) {
        int idx = i * 256 + tid;
        int rl = idx >> 6, cl = idx & 63;
        tile[rl][cl] = (bf16)src[(size_t)(tr * 64 + rl) * 1024 + tc * 64 + cl];
    }
    __syncthreads();
    #pragma unroll
    for (int i = 0; i < 16; i++) {
        int idx = i * 256 + tid;
        int rl = idx >> 6, cl = idx & 63;
        dst[(size_t)(tc * 64 + rl) * 1024 + tr * 64 + cl] = tile[cl][rl];
    }
}

// bias concat (fp32): [b_q | b_k | b_v] -> 3072 floats
__global__ void biascat_kernel(const float* __restrict__ bq, const float* __restrict__ bk,
                               const float* __restrict__ bv, float* __restrict__ dst)
{
    int i = blockIdx.x * 256 + threadIdx.x;
    if (i < 1024) dst[i] = bq[i];
    else if (i < 2048) dst[i] = bk[i - 1024];
    else dst[i] = bv[i - 2048];
}

// =====================================================================
// m97-style GEMM: A bf16, BT bf16, global_load_lds(16B) staging.
// C = A @ BT^T + bias, bf16 out; cols<1024 scaled by QSCALE if scaleQ
// (folds 1/sqrt(d_k) * log2(e) into Q so softmax is a bare exp2).
// =====================================================================
#define QSCALE 0.18033688011112043f   // 0.125 * log2(e)
__global__ __launch_bounds__(256) void gemm_bf16_kernel(
    const bf16* __restrict__ A, const bf16* __restrict__ BT,
    const float* __restrict__ bias, bf16* __restrict__ C,
    int M, int N, int K, int scaleQ)
{
    __shared__ bf16 sA[128 * 32];
    __shared__ bf16 sB[128 * 32];
    const int tid  = threadIdx.x;
    const int lane = tid & 63;
    const int wave = tid >> 6;
    const int quad = lane >> 4;
    const int l15  = lane & 15;
    const int wm = (wave >> 1) * 64;
    const int wn = (wave & 1) * 64;
    const int m0 = blockIdx.y * 128;
    const int n0 = blockIdx.x * 128;

    const f32x4 fzero = {0.f, 0.f, 0.f, 0.f};
    f32x4 acc[4][4];
    #pragma unroll
    for (int i = 0; i < 4; i++)
        #pragma unroll
        for (int j = 0; j < 4; j++) acc[i][j] = fzero;

    float bv[4];
    #pragma unroll
    for (int nc = 0; nc < 4; nc++) bv[nc] = bias[n0 + wn + nc * 16 + l15];

    const int rA = lane >> 2;
    const int cA = (lane & 3) * 8;

    for (int k0 = 0; k0 < K; k0 += 32) {
        #pragma unroll
        for (int p = 0; p < 2; p++) {
            int r16 = (wave * 2 + p) * 16;
            gll16(&A[(size_t)(m0 + r16 + rA) * K + k0 + cA], &sA[r16 * 32]);
            gll16(&BT[(size_t)(n0 + r16 + rA) * K + k0 + cA], &sB[r16 * 32]);
        }
        __syncthreads();

        bf16x8 aF[4], bF[4];
        #pragma unroll
        for (int mc = 0; mc < 4; mc++)
            aF[mc] = *(const bf16x8*)&sA[(wm + mc * 16 + l15) * 32 + quad * 8];
        #pragma unroll
        for (int nc = 0; nc < 4; nc++)
            bF[nc] = *(const bf16x8*)&sB[(wn + nc * 16 + l15) * 32 + quad * 8];

        #pragma unroll
        for (int mc = 0; mc < 4; mc++)
            #pragma unroll
            for (int nc = 0; nc < 4; nc++)
                acc[mc][nc] = mfma16(aF[mc], bF[nc], acc[mc][nc]);
        __syncthreads();
    }

    const float sc = (scaleQ && n0 < 1024) ? QSCALE : 1.0f;
    #pragma unroll
    for (int mc = 0; mc < 4; mc++) {
        #pragma unroll
        for (int reg = 0; reg < 4; reg++) {
            int row = m0 + wm + mc * 16 + quad * 4 + reg;
            size_t base = (size_t)row * N + n0 + wn;
            #pragma unroll
            for (int nc = 0; nc < 4; nc++)
                C[base + nc * 16 + l15] = (bf16)((acc[mc][nc][reg] + bv[nc]) * sc);
        }
    }
}

// Same structure, fp32 output (final projection -> d_out)
__global__ __launch_bounds__(256) void gemm_bf16_f32out_kernel(
    const bf16* __restrict__ A, const bf16* __restrict__ BT,
    const float* __restrict__ bias, float* __restrict__ C,
    int M, int N, int K)
{
    __shared__ bf16 sA[128 * 32];
    __shared__ bf16 sB[128 * 32];
    const int tid  = threadIdx.x;
    const int lane = tid & 63;
    const int wave = tid >> 6;
    const int quad = lane >> 4;
    const int l15  = lane & 15;
    const int wm = (wave >> 1) * 64;
    const int wn = (wave & 1) * 64;
    const int m0 = blockIdx.y * 128;
    const int n0 = blockIdx.x * 128;

    const f32x4 fzero = {0.f, 0.f, 0.f, 0.f};
    f32x4 acc[4][4];
    #pragma unroll
    for (int i = 0; i < 4; i++)
        #pragma unroll
        for (int j = 0; j < 4; j++) acc[i][j] = fzero;

    float bv[4];
    #pragma unroll
    for (int nc = 0; nc < 4; nc++) bv[nc] = bias[n0 + wn + nc * 16 + l15];

    const int rA = lane >> 2;
    const int cA = (lane & 3) * 8;

    for (int k0 = 0; k0 < K; k0 += 32) {
        #pragma unroll
        for (int p = 0; p < 2; p++) {
            int r16 = (wave * 2 + p) * 16;
            gll16(&A[(size_t)(m0 + r16 + rA) * K + k0 + cA], &sA[r16 * 32]);
            gll16(&BT[(size_t)(n0 + r16 + rA) * K + k0 + cA], &sB[r16 * 32]);
        }
        __syncthreads();

        bf16x8 aF[4], bF[4];
        #pragma unroll
        for (int mc = 0; mc < 4; mc++)
            aF[mc] = *(const bf16x8*)&sA[(wm + mc * 16 + l15) * 32 + quad * 8];
        #pragma unroll
        for (int nc = 0; nc < 4; nc++)
            bF[nc] = *(const bf16x8*)&sB[(wn + nc * 16 + l15) * 32 + quad * 8];

        #pragma unroll
        for (int mc = 0; mc < 4; mc++)
            #pragma unroll
            for (int nc = 0; nc < 4; nc++)
                acc[mc][nc] = mfma16(aF[mc], bF[nc], acc[mc][nc]);
        __syncthreads();
    }

    #pragma unroll
    for (int mc = 0; mc < 4; mc++) {
        #pragma unroll
        for (int reg = 0; reg < 4; reg++) {
            int row = m0 + wm + mc * 16 + quad * 4 + reg;
            size_t base = (size_t)row * N + n0 + wn;
            #pragma unroll
            for (int nc = 0; nc < 4; nc++)
                C[base + nc * 16 + l15] = acc[mc][nc][reg] + bv[nc];
        }
    }
}

// =====================================================================
// V transpose: QKVp[b][n][2048 + h*64 + d] -> Vt[b*16+h][d][n]
// =====================================================================
__global__ __launch_bounds__(256) void vtrans_kernel(
    const bf16* __restrict__ QKVp, bf16* __restrict__ Vt)
{
    __shared__ bf16 tile[64][65];
    const int bid = blockIdx.x;
    const int bh = bid >> 5;
    const int nt = bid & 31;
    const int b = bh >> 4, h = bh & 15;
    const int tid = threadIdx.x;

    #pragma unroll
    for (int i = 0; i < 16; i++) {
        int idx = i * 256 + tid;
        int rl = idx >> 6, cl = idx & 63;
        tile[rl][cl] = QKVp[(size_t)(b * 2048 + nt * 64 + rl) * 3072 + 2048 + h * 64 + cl];
    }
    __syncthreads();
    #pragma unroll
    for (int i = 0; i < 16; i++) {
        int idx = i * 256 + tid;
        int rl = idx >> 6, cl = idx & 63;
        Vt[((size_t)bh * 64 + rl) * 2048 + nt * 64 + cl] = tile[cl][rl];
    }
}

// =====================================================================
// Flash attention, P-in-registers (no sP LDS round-trip):
//   S^T = K·Q^T  (A = permuted sK rows, B = Q frags)
//   P^T = exp2(S^T) packed in-register -> B-operand of O^T = V^T·P
//   O^T C-layout: col=l15=q, row=quad*4+r=d-local
// Key-row permute: S^T tile c covers keys (m>>2)*8+(c&1)*4+(m&3)+32(c>>1)
// so lane `quad` holds exactly keys quad*8+j needed by the PV B-frag.
// Swizzle: phys_granule = logical ^ sw(row), sw(row)=(row&3)|(((row>>3)&1)<<2)
// -> all LDS ops <=2 lanes/bank (free).  LDS = 16 KB/block.
// =====================================================================
__global__ __launch_bounds__(256) void attn_kernel(
    const bf16* __restrict__ QKV, const bf16* __restrict__ Vt,
    bf16* __restrict__ Opre)
{
    __shared__ bf16 sK[64 * 64];      // [key][d], swizzled
    __shared__ bf16 sV[64 * 64];      // [d][key], swizzled

    const int tid  = threadIdx.x;
    const int lane = tid & 63;
    const int w    = tid >> 6;
    const int quad = lane >> 4;
    const int l15  = lane & 15;
    const int bid = blockIdx.x;
    const int bh = bid >> 5;        // 0..63
    const int qt = bid & 31;
    const int b = bh >> 4, h = bh & 15;
    const int q0 = qt * 64;

    // Q fragments as B-operand [n=q][k=d]: lane l15 = q, k = quad*8+j.
    // (identical memory pattern to the old A-frag load; Q pre-scaled)
    size_t qrow = (size_t)(b * 2048 + q0 + w * 16 + l15) * 3072 + h * 64;
    bf16x8 qF0 = *(const bf16x8*)&QKV[qrow + quad * 8];
    bf16x8 qF1 = *(const bf16x8*)&QKV[qrow + 32 + quad * 8];

    const f32x4 fzero = {0.f, 0.f, 0.f, 0.f};
    float psum = 0.f;
    f32x4 o[4];
    #pragma unroll
    for (int mt = 0; mt < 4; mt++) o[mt] = fzero;

    const int srow = tid >> 3, sseg = tid & 7;    // staging: 64 rows x 8 granules
    const size_t kbase = (size_t)(b * 2048) * 3072 + 1024 + h * 64;
    const size_t vbase = (size_t)bh * 64 * 2048;

    // swizzle factors (row-dependent parts are l15-only -> hoisted)
    const int swk = (l15 & 3) | (((l15 >> 2) & 1) << 2);  // for S^T K-rows
    const int swv = (l15 & 3) | (((l15 >> 3) & 1) << 2);  // for V rows mt*16+l15

    for (int key0 = 0; key0 < 2048; key0 += 64) {
        #pragma unroll
        for (int p = 0; p < 2; p++) {
            int row = srow + p * 32;
            int sg = sseg ^ ((row & 3) | (((row >> 3) & 1) << 2));
            *(bf16x8*)&sK[row * 64 + sg * 8] =
                *(const bf16x8*)&QKV[kbase + (size_t)(key0 + row) * 3072 + sseg * 8];
            *(bf16x8*)&sV[row * 64 + sg * 8] =
                *(const bf16x8*)&Vt[vbase + (size_t)row * 2048 + key0 + sseg * 8];
        }
        __syncthreads();

        // S^T tiles c=0..3: A-rows kr = (l15>>2)*8 + (c&1)*4 + (l15&3) + (c>>1)*32
        f32x4 st[4];
        #pragma unroll
        for (int c = 0; c < 4; c++) {
            int kr = ((l15 >> 2) << 3) + ((c & 1) << 2) + (l15 & 3) + ((c >> 1) << 5);
            bf16x8 kA0 = *(const bf16x8*)&sK[kr * 64 + ((quad ^ swk) * 8)];
            bf16x8 kA1 = *(const bf16x8*)&sK[kr * 64 + (((4 + quad) ^ swk) * 8)];
            st[c] = mfma16(kA0, qF0, fzero);
            st[c] = mfma16(kA1, qF1, st[c]);
        }

        // P^T = exp2(S^T); pack directly into PV B-fragments; row-sums local
        bf16x8 pB0, pB1;
        #pragma unroll
        for (int r = 0; r < 4; r++) {
            float p0 = __builtin_amdgcn_exp2f(st[0][r]);
            float p1 = __builtin_amdgcn_exp2f(st[1][r]);
            float p2 = __builtin_amdgcn_exp2f(st[2][r]);
            float p3 = __builtin_amdgcn_exp2f(st[3][r]);
            psum += (p0 + p1) + (p2 + p3);
            pB0[r]     = (bf16)p0;
            pB0[4 + r] = (bf16)p1;
            pB1[r]     = (bf16)p2;
            pB1[4 + r] = (bf16)p3;
        }

        // O^T += V^T · P : A = sV rows (m=d), B = packed P frags
        #pragma unroll
        for (int mt = 0; mt < 4; mt++) {
            int vr = mt * 16 + l15;
            bf16x8 vA0 = *(const bf16x8*)&sV[vr * 64 + ((quad ^ swv) * 8)];
            bf16x8 vA1 = *(const bf16x8*)&sV[vr * 64 + (((4 + quad) ^ swv) * 8)];
            o[mt] = mfma16(vA0, pB0, o[mt]);
            o[mt] = mfma16(vA1, pB1, o[mt]);
        }
        __syncthreads();   // before next tile overwrites sK/sV
    }

    // row-sum: lane holds 16-key partials for q=l15; reduce across quads
    psum += __shfl_xor(psum, 16);
    psum += __shfl_xor(psum, 32);
    float inv = 1.0f / psum;

    // O^T C-layout: col=l15=q, row=quad*4+r = d-local of tile mt
    size_t obase = (size_t)(b * 2048 + q0 + w * 16 + l15) * 1024 + h * 64;
    #pragma unroll
    for (int mt = 0; mt < 4; mt++) {
        bf16x4 ov = {(bf16)(o[mt][0] * inv), (bf16)(o[mt][1] * inv),
                     (bf16)(o[mt][2] * inv), (bf16)(o[mt][3] * inv)};
        *(bf16x4*)&Opre[obase + mt * 16 + quad * 4] = ov;
    }
}

// =====================================================================
extern "C" void kernel_launch(void* const* d_in, const int* in_sizes, int n_in,
                              void* d_out, int out_size, void* d_ws, size_t ws_size,
                              hipStream_t stream)
{
    const float* x  = (const float*)d_in[0];
    const float* Wq = (const float*)d_in[1];
    const float* bq = (const float*)d_in[2];
    const float* Wk = (const float*)d_in[3];
    const float* bk = (const float*)d_in[4];
    const float* Wv = (const float*)d_in[5];
    const float* bv = (const float*)d_in[6];
    const float* Wo = (const float*)d_in[7];
    const float* bo = (const float*)d_in[8];
    float* out = (float*)d_out;

    bf16* WTqkv = (bf16*)d_ws;                         // 3072*1024 bf16
    bf16* WTo   = WTqkv + (size_t)3072 * 1024;         // 1024*1024 bf16
    float* bcat = (float*)(WTo + (size_t)1024 * 1024); // 3072 f32 (pad 4096)
    bf16* QKVp  = (bf16*)(bcat + 4096);                // 8192*3072 bf16
    bf16* Vt    = QKVp + (size_t)8192 * 3072;          // 64*64*2048 bf16
    bf16* Apre  = Vt + (size_t)64 * 64 * 2048;         // 8192*1024 bf16
    bf16* xb    = Apre;   // alias: x-as-bf16 lives here until attn overwrites
    (void)ws_size; (void)n_in; (void)in_sizes; (void)out_size;

    xcvt_kernel<<<4096, 256, 0, stream>>>(x, xb);
    wtrans_kernel<<<1024, 256, 0, stream>>>(Wq, Wk, Wv, Wo, WTqkv, WTo);
    biascat_kernel<<<12, 256, 0, stream>>>(bq, bk, bv, bcat);
    gemm_bf16_kernel<<<dim3(24, 64), 256, 0, stream>>>(xb, WTqkv, bcat, QKVp, 8192, 3072, 1024, 1);
    vtrans_kernel<<<2048, 256, 0, stream>>>(QKVp, Vt);
    attn_kernel<<<2048, 256, 0, stream>>>(QKVp, Vt, Apre);
    gemm_bf16_f32out_kernel<<<dim3(8, 64), 256, 0, stream>>>(Apre, WTo, bo, out, 8192, 1024, 1024);
}

// Round 8
// 307.777 us; speedup vs baseline: 1.2365x; 1.0952x over previous
//
#include <hip/hip_runtime.h>

typedef __bf16 bf16;
typedef __attribute__((ext_vector_type(8))) __bf16 bf16x8;
typedef __attribute__((ext_vector_type(4))) __bf16 bf16x4;
typedef __attribute__((ext_vector_type(4))) float f32x4;

static __device__ __forceinline__ f32x4 mfma16(bf16x8 a, bf16x8 b, f32x4 c) {
    return __builtin_amdgcn_mfma_f32_16x16x32_bf16(a, b, c, 0, 0, 0);
}

// async global->LDS, 16B per lane; lds base must be wave-uniform
static __device__ __forceinline__ void gll16(const bf16* g, bf16* l) {
    __builtin_amdgcn_global_load_lds(
        (const __attribute__((address_space(1))) unsigned int*)g,
        (__attribute__((address_space(3))) unsigned int*)l, 16, 0, 0);
}

// =====================================================================
// x fp32 -> bf16 (once; result aliased into the Apre workspace slot)
// =====================================================================
__global__ __launch_bounds__(256) void xcvt_kernel(
    const float* __restrict__ x, bf16* __restrict__ xb)
{
    size_t i = ((size_t)blockIdx.x * 256 + threadIdx.x) * 8;
    float4 a0 = *(const float4*)&x[i];
    float4 a1 = *(const float4*)&x[i + 4];
    bf16x8 v = {(bf16)a0.x, (bf16)a0.y, (bf16)a0.z, (bf16)a0.w,
                (bf16)a1.x, (bf16)a1.y, (bf16)a1.z, (bf16)a1.w};
    *(bf16x8*)&xb[i] = v;
}

// =====================================================================
// Weight transpose + convert: W[k][n] (1024x1024 fp32) -> WT[n][k] (bf16)
// =====================================================================
__global__ __launch_bounds__(256) void wtrans_kernel(
    const float* __restrict__ Wq, const float* __restrict__ Wk,
    const float* __restrict__ Wv, const float* __restrict__ Wo,
    bf16* __restrict__ WTqkv, bf16* __restrict__ WTo)
{
    __shared__ bf16 tile[64][65];
    const int bid = blockIdx.x;
    const int mi = bid >> 8;
    const int t  = bid & 255;
    const int tr = t >> 4;
    const int tc = t & 15;
    const int tid = threadIdx.x;

    const float* src = (mi == 0) ? Wq : (mi == 1) ? Wk : (mi == 2) ? Wv : Wo;
    bf16* dst = (mi < 3) ? (WTqkv + (size_t)mi * 1024 * 1024) : WTo;

    #pragma unroll
    for (int i = 0; i < 16; i++) {
        int idx = i * 256 + tid;
        int rl = idx >> 6, cl = idx & 63;
        tile[rl][cl] = (bf16)src[(size_t)(tr * 64 + rl) * 1024 + tc * 64 + cl];
    }
    __syncthreads();
    #pragma unroll
    for (int i = 0; i < 16; i++) {
        int idx = i * 256 + tid;
        int rl = idx >> 6, cl = idx & 63;
        dst[(size_t)(tc * 64 + rl) * 1024 + tr * 64 + cl] = tile[cl][rl];
    }
}

// bias concat (fp32): [b_q | b_k | b_v] -> 3072 floats
__global__ void biascat_kernel(const float* __restrict__ bq, const float* __restrict__ bk,
                               const float* __restrict__ bv, float* __restrict__ dst)
{
    int i = blockIdx.x * 256 + threadIdx.x;
    if (i < 1024) dst[i] = bq[i];
    else if (i < 2048) dst[i] = bk[i - 1024];
    else dst[i] = bv[i - 2048];
}

// =====================================================================
// m97-style GEMM: A bf16, BT bf16, global_load_lds(16B) staging.
// C = A @ BT^T + bias, bf16 out; cols<1024 scaled by QSCALE if scaleQ
// (folds 1/sqrt(d_k) * log2(e) into Q so softmax is a bare exp2).
// =====================================================================
#define QSCALE 0.18033688011112043f   // 0.125 * log2(e)
__global__ __launch_bounds__(256) void gemm_bf16_kernel(
    const bf16* __restrict__ A, const bf16* __restrict__ BT,
    const float* __restrict__ bias, bf16* __restrict__ C,
    int M, int N, int K, int scaleQ)
{
    __shared__ bf16 sA[128 * 32];
    __shared__ bf16 sB[128 * 32];
    const int tid  = threadIdx.x;
    const int lane = tid & 63;
    const int wave = tid >> 6;
    const int quad = lane >> 4;
    const int l15  = lane & 15;
    const int wm = (wave >> 1) * 64;
    const int wn = (wave & 1) * 64;
    const int m0 = blockIdx.y * 128;
    const int n0 = blockIdx.x * 128;

    const f32x4 fzero = {0.f, 0.f, 0.f, 0.f};
    f32x4 acc[4][4];
    #pragma unroll
    for (int i = 0; i < 4; i++)
        #pragma unroll
        for (int j = 0; j < 4; j++) acc[i][j] = fzero;

    float bv[4];
    #pragma unroll
    for (int nc = 0; nc < 4; nc++) bv[nc] = bias[n0 + wn + nc * 16 + l15];

    const int rA = lane >> 2;
    const int cA = (lane & 3) * 8;

    for (int k0 = 0; k0 < K; k0 += 32) {
        #pragma unroll
        for (int p = 0; p < 2; p++) {
            int r16 = (wave * 2 + p) * 16;
            gll16(&A[(size_t)(m0 + r16 + rA) * K + k0 + cA], &sA[r16 * 32]);
            gll16(&BT[(size_t)(n0 + r16 + rA) * K + k0 + cA], &sB[r16 * 32]);
        }
        __syncthreads();

        bf16x8 aF[4], bF[4];
        #pragma unroll
        for (int mc = 0; mc < 4; mc++)
            aF[mc] = *(const bf16x8*)&sA[(wm + mc * 16 + l15) * 32 + quad * 8];
        #pragma unroll
        for (int nc = 0; nc < 4; nc++)
            bF[nc] = *(const bf16x8*)&sB[(wn + nc * 16 + l15) * 32 + quad * 8];

        #pragma unroll
        for (int mc = 0; mc < 4; mc++)
            #pragma unroll
            for (int nc = 0; nc < 4; nc++)
                acc[mc][nc] = mfma16(aF[mc], bF[nc], acc[mc][nc]);
        __syncthreads();
    }

    const float sc = (scaleQ && n0 < 1024) ? QSCALE : 1.0f;
    #pragma unroll
    for (int mc = 0; mc < 4; mc++) {
        #pragma unroll
        for (int reg = 0; reg < 4; reg++) {
            int row = m0 + wm + mc * 16 + quad * 4 + reg;
            size_t base = (size_t)row * N + n0 + wn;
            #pragma unroll
            for (int nc = 0; nc < 4; nc++)
                C[base + nc * 16 + l15] = (bf16)((acc[mc][nc][reg] + bv[nc]) * sc);
        }
    }
}

// Same structure, fp32 output (final projection -> d_out)
__global__ __launch_bounds__(256) void gemm_bf16_f32out_kernel(
    const bf16* __restrict__ A, const bf16* __restrict__ BT,
    const float* __restrict__ bias, float* __restrict__ C,
    int M, int N, int K)
{
    __shared__ bf16 sA[128 * 32];
    __shared__ bf16 sB[128 * 32];
    const int tid  = threadIdx.x;
    const int lane = tid & 63;
    const int wave = tid >> 6;
    const int quad = lane >> 4;
    const int l15  = lane & 15;
    const int wm = (wave >> 1) * 64;
    const int wn = (wave & 1) * 64;
    const int m0 = blockIdx.y * 128;
    const int n0 = blockIdx.x * 128;

    const f32x4 fzero = {0.f, 0.f, 0.f, 0.f};
    f32x4 acc[4][4];
    #pragma unroll
    for (int i = 0; i < 4; i++)
        #pragma unroll
        for (int j = 0; j < 4; j++) acc[i][j] = fzero;

    float bv[4];
    #pragma unroll
    for (int nc = 0; nc < 4; nc++) bv[nc] = bias[n0 + wn + nc * 16 + l15];

    const int rA = lane >> 2;
    const int cA = (lane & 3) * 8;

    for (int k0 = 0; k0 < K; k0 += 32) {
        #pragma unroll
        for (int p = 0; p < 2; p++) {
            int r16 = (wave * 2 + p) * 16;
            gll16(&A[(size_t)(m0 + r16 + rA) * K + k0 + cA], &sA[r16 * 32]);
            gll16(&BT[(size_t)(n0 + r16 + rA) * K + k0 + cA], &sB[r16 * 32]);
        }
        __syncthreads();

        bf16x8 aF[4], bF[4];
        #pragma unroll
        for (int mc = 0; mc < 4; mc++)
            aF[mc] = *(const bf16x8*)&sA[(wm + mc * 16 + l15) * 32 + quad * 8];
        #pragma unroll
        for (int nc = 0; nc < 4; nc++)
            bF[nc] = *(const bf16x8*)&sB[(wn + nc * 16 + l15) * 32 + quad * 8];

        #pragma unroll
        for (int mc = 0; mc < 4; mc++)
            #pragma unroll
            for (int nc = 0; nc < 4; nc++)
                acc[mc][nc] = mfma16(aF[mc], bF[nc], acc[mc][nc]);
        __syncthreads();
    }

    #pragma unroll
    for (int mc = 0; mc < 4; mc++) {
        #pragma unroll
        for (int reg = 0; reg < 4; reg++) {
            int row = m0 + wm + mc * 16 + quad * 4 + reg;
            size_t base = (size_t)row * N + n0 + wn;
            #pragma unroll
            for (int nc = 0; nc < 4; nc++)
                C[base + nc * 16 + l15] = acc[mc][nc][reg] + bv[nc];
        }
    }
}

// =====================================================================
// V transpose: QKVp[b][n][2048 + h*64 + d] -> Vt[b*16+h][d][n]
// =====================================================================
__global__ __launch_bounds__(256) void vtrans_kernel(
    const bf16* __restrict__ QKVp, bf16* __restrict__ Vt)
{
    __shared__ bf16 tile[64][65];
    const int bid = blockIdx.x;
    const int bh = bid >> 5;
    const int nt = bid & 31;
    const int b = bh >> 4, h = bh & 15;
    const int tid = threadIdx.x;

    #pragma unroll
    for (int i = 0; i < 16; i++) {
        int idx = i * 256 + tid;
        int rl = idx >> 6, cl = idx & 63;
        tile[rl][cl] = QKVp[(size_t)(b * 2048 + nt * 64 + rl) * 3072 + 2048 + h * 64 + cl];
    }
    __syncthreads();
    #pragma unroll
    for (int i = 0; i < 16; i++) {
        int idx = i * 256 + tid;
        int rl = idx >> 6, cl = idx & 63;
        Vt[((size_t)bh * 64 + rl) * 2048 + nt * 64 + cl] = tile[cl][rl];
    }
}

// =====================================================================
// Flash attention, P-in-registers, 32 q-rows per wave (2 Q-groups):
// K/V fragments loaded once per wave feed both Q-groups -> LDS frag
// traffic per q halves vs 16q/wave.  Block = (b,h, 128 q): 4 waves.
//   S^T = K·Q^T ; P^T = exp2(S^T) packed in-register as PV B-operand
//   O^T = V^T·P ; C-layout col=l15=q, row=quad*4+r=d-local
// Key-row permute: S^T tile c covers keys (m>>2)*8+(c&1)*4+(m&3)+32(c>>1)
// Swizzle: phys_granule = logical ^ sw(row), sw(row)=(row&3)|(((row>>3)&1)<<2)
// -> all LDS ops <=2 lanes/bank (free).  LDS = 16 KB/block.
// =====================================================================
__global__ __launch_bounds__(256) void attn_kernel(
    const bf16* __restrict__ QKV, const bf16* __restrict__ Vt,
    bf16* __restrict__ Opre)
{
    __shared__ bf16 sK[64 * 64];      // [key][d], swizzled
    __shared__ bf16 sV[64 * 64];      // [d][key], swizzled

    const int tid  = threadIdx.x;
    const int lane = tid & 63;
    const int w    = tid >> 6;
    const int quad = lane >> 4;
    const int l15  = lane & 15;
    const int bid = blockIdx.x;
    const int bh = bid >> 4;        // 0..63
    const int qt = bid & 15;
    const int b = bh >> 4, h = bh & 15;
    const int q0 = qt * 128;

    // Q fragments as B-operand [n=q][k=d], two 16-row groups (Q pre-scaled)
    bf16x8 qF[2][2];
    #pragma unroll
    for (int g = 0; g < 2; g++) {
        size_t qrow = (size_t)(b * 2048 + q0 + w * 32 + g * 16 + l15) * 3072 + h * 64;
        qF[g][0] = *(const bf16x8*)&QKV[qrow + quad * 8];
        qF[g][1] = *(const bf16x8*)&QKV[qrow + 32 + quad * 8];
    }

    const f32x4 fzero = {0.f, 0.f, 0.f, 0.f};
    float psum[2] = {0.f, 0.f};
    f32x4 o[2][4];
    #pragma unroll
    for (int g = 0; g < 2; g++)
        #pragma unroll
        for (int mt = 0; mt < 4; mt++) o[g][mt] = fzero;

    const int srow = tid >> 3, sseg = tid & 7;    // staging: 64 rows x 8 granules
    const size_t kbase = (size_t)(b * 2048) * 3072 + 1024 + h * 64;
    const size_t vbase = (size_t)bh * 64 * 2048;

    // swizzle factors (row-dependent parts are l15-only -> hoisted)
    const int swk = (l15 & 3) | (((l15 >> 2) & 1) << 2);  // for S^T K-rows
    const int swv = (l15 & 3) | (((l15 >> 3) & 1) << 2);  // for V rows mt*16+l15

    for (int key0 = 0; key0 < 2048; key0 += 64) {
        #pragma unroll
        for (int p = 0; p < 2; p++) {
            int row = srow + p * 32;
            int sg = sseg ^ ((row & 3) | (((row >> 3) & 1) << 2));
            *(bf16x8*)&sK[row * 64 + sg * 8] =
                *(const bf16x8*)&QKV[kbase + (size_t)(key0 + row) * 3072 + sseg * 8];
            *(bf16x8*)&sV[row * 64 + sg * 8] =
                *(const bf16x8*)&Vt[vbase + (size_t)row * 2048 + key0 + sseg * 8];
        }
        __syncthreads();

        // S^T tiles c=0..3, keys permuted; K frags shared across both q-groups.
        // Consume each S^T tile immediately (keeps VGPR pressure low).
        bf16x8 pB[2][2];
        #pragma unroll
        for (int c = 0; c < 4; c++) {
            int kr = ((l15 >> 2) << 3) + ((c & 1) << 2) + (l15 & 3) + ((c >> 1) << 5);
            bf16x8 kA0 = *(const bf16x8*)&sK[kr * 64 + ((quad ^ swk) * 8)];
            bf16x8 kA1 = *(const bf16x8*)&sK[kr * 64 + (((4 + quad) ^ swk) * 8)];
            #pragma unroll
            for (int g = 0; g < 2; g++) {
                f32x4 st = mfma16(kA0, qF[g][0], fzero);
                st = mfma16(kA1, qF[g][1], st);
                #pragma unroll
                for (int r = 0; r < 4; r++) {
                    float p = __builtin_amdgcn_exp2f(st[r]);
                    psum[g] += p;
                    pB[g][c >> 1][(c & 1) * 4 + r] = (bf16)p;
                }
            }
        }

        // O^T += V^T · P : V frags shared across both q-groups
        #pragma unroll
        for (int mt = 0; mt < 4; mt++) {
            int vr = mt * 16 + l15;
            bf16x8 vA0 = *(const bf16x8*)&sV[vr * 64 + ((quad ^ swv) * 8)];
            bf16x8 vA1 = *(const bf16x8*)&sV[vr * 64 + (((4 + quad) ^ swv) * 8)];
            #pragma unroll
            for (int g = 0; g < 2; g++) {
                o[g][mt] = mfma16(vA0, pB[g][0], o[g][mt]);
                o[g][mt] = mfma16(vA1, pB[g][1], o[g][mt]);
            }
        }
        __syncthreads();   // before next tile overwrites sK/sV
    }

    // row-sum: lane holds 16-key partials for q=l15 (per group); reduce quads
    #pragma unroll
    for (int g = 0; g < 2; g++) {
        float t = psum[g];
        t += __shfl_xor(t, 16);
        t += __shfl_xor(t, 32);
        float inv = 1.0f / t;
        size_t obase = (size_t)(b * 2048 + q0 + w * 32 + g * 16 + l15) * 1024 + h * 64;
        #pragma unroll
        for (int mt = 0; mt < 4; mt++) {
            bf16x4 ov = {(bf16)(o[g][mt][0] * inv), (bf16)(o[g][mt][1] * inv),
                         (bf16)(o[g][mt][2] * inv), (bf16)(o[g][mt][3] * inv)};
            *(bf16x4*)&Opre[obase + mt * 16 + quad * 4] = ov;
        }
    }
}

// =====================================================================
extern "C" void kernel_launch(void* const* d_in, const int* in_sizes, int n_in,
                              void* d_out, int out_size, void* d_ws, size_t ws_size,
                              hipStream_t stream)
{
    const float* x  = (const float*)d_in[0];
    const float* Wq = (const float*)d_in[1];
    const float* bq = (const float*)d_in[2];
    const float* Wk = (const float*)d_in[3];
    const float* bk = (const float*)d_in[4];
    const float* Wv = (const float*)d_in[5];
    const float* bv = (const float*)d_in[6];
    const float* Wo = (const float*)d_in[7];
    const float* bo = (const float*)d_in[8];
    float* out = (float*)d_out;

    bf16* WTqkv = (bf16*)d_ws;                         // 3072*1024 bf16
    bf16* WTo   = WTqkv + (size_t)3072 * 1024;         // 1024*1024 bf16
    float* bcat = (float*)(WTo + (size_t)1024 * 1024); // 3072 f32 (pad 4096)
    bf16* QKVp  = (bf16*)(bcat + 4096);                // 8192*3072 bf16
    bf16* Vt    = QKVp + (size_t)8192 * 3072;          // 64*64*2048 bf16
    bf16* Apre  = Vt + (size_t)64 * 64 * 2048;         // 8192*1024 bf16
    bf16* xb    = Apre;   // alias: x-as-bf16 lives here until attn overwrites
    (void)ws_size; (void)n_in; (void)in_sizes; (void)out_size;

    xcvt_kernel<<<4096, 256, 0, stream>>>(x, xb);
    wtrans_kernel<<<1024, 256, 0, stream>>>(Wq, Wk, Wv, Wo, WTqkv, WTo);
    biascat_kernel<<<12, 256, 0, stream>>>(bq, bk, bv, bcat);
    gemm_bf16_kernel<<<dim3(24, 64), 256, 0, stream>>>(xb, WTqkv, bcat, QKVp, 8192, 3072, 1024, 1);
    vtrans_kernel<<<2048, 256, 0, stream>>>(QKVp, Vt);
    attn_kernel<<<1024, 256, 0, stream>>>(QKVp, Vt, Apre);
    gemm_bf16_f32out_kernel<<<dim3(8, 64), 256, 0, stream>>>(Apre, WTo, bo, out, 8192, 1024, 1024);
}